// Round 10
// baseline (755.191 us; speedup 1.0000x reference)
//
#include <hip/hip_runtime.h>

#define HWD 884736   // 96*96*96
#define KCLS 5
#define CCH 64
#define NC 4

constexpr int PLANE4 = HWD / 4;          // float4 groups per channel plane (221184)
constexpr int GRP_B  = HWD / 4;          // voxel-groups per batch item
constexpr int NBLK   = 2 * GRP_B / 256;  // 1728 blocks of 256 groups
constexpr int NPART  = 16;
constexpr int PARTSZ = 272;              // 256 sums + 4 cnt @256 + 4 sq @260

__global__ __launch_bounds__(256) void pm_zero(float* __restrict__ part) {
    const int n = NPART * PARTSZ;
    for (int i = threadIdx.x; i < n; i += 256) part[i] = 0.f;
}

// Fused: mask (pred/label -> 3b/voxel in LDS) + predicated dense feat sweep.
// Inactive lanes (no masked voxel in their float4-group) issue no feat loads;
// dense ordering is preserved so the line stream stays page-local.
__global__ __launch_bounds__(256, 3) void pm_main(
    const float* __restrict__ feat, const float* __restrict__ pred,
    const int* __restrict__ label, const unsigned char* __restrict__ is_lab,
    float* __restrict__ part)
{
    __shared__ unsigned int smask[256];
    __shared__ float lcnt[NC];

    const int t = threadIdx.x, w = t >> 6, l = t & 63;
    const int bi = blockIdx.x;
    const int b = (bi >= NBLK / 2);                  // block never straddles batch
    const int g0 = bi * 256 - b * GRP_B;             // group base within batch plane

    if (t < NC) lcnt[t] = 0.f;
    __syncthreads();

    // ---- phase A: mask from pred/label (coalesced), one group per thread ----
    {
        const int gg = g0 + t;
        const float4* pb = (const float4*)(pred + (size_t)b * KCLS * HWD) + gg;
        float4 pk[KCLS];
        #pragma unroll
        for (int k = 0; k < KCLS; ++k) pk[k] = pb[(size_t)k * PLANE4];
        const int4 lb = ((const int4*)(label + (size_t)b * HWD))[gg];
        const bool lab = is_lab[b] != 0;

        unsigned int wd = 0;
        #pragma unroll
        for (int j = 0; j < 4; ++j) {
            float best = -1.f; int c = 0;
            #pragma unroll
            for (int k = 0; k < KCLS; ++k) {
                float v = ((const float*)&pk[k])[j];
                if (v > best) { best = v; c = k; }   // first-max == jnp.argmax
            }
            const int lj = ((const int*)&lb)[j];
            const bool m = (best > 0.8f) & (c > 0) & ((c == lj) | (!lab));
            if (m) {
                wd |= (4u | (unsigned)(c - 1)) << (3 * j);
                atomicAdd(&lcnt[c - 1], 1.f);
            }
        }
        smask[t] = wd;
    }
    __syncthreads();

    // ---- phase B: predicated dense sweep; wave w owns channels [16w,16w+16) ----
    const float4* fb = (const float4*)feat + (size_t)b * CCH * PLANE4;
    const int c0 = w * 16;

    float acc[64];                        // [u*4 + k]: channel-in-wave u, class k
    #pragma unroll
    for (int i = 0; i < 64; ++i) acc[i] = 0.f;
    float sq[NC] = {0.f, 0.f, 0.f, 0.f};

    for (int i = 0; i < 4; ++i) {
        const int gl = i * 64 + l;                   // group within block
        const int gg = g0 + gl;
        const unsigned int wm = smask[gl];
        const bool act = (wm != 0);

        float ind[4][NC];
        #pragma unroll
        for (int j = 0; j < 4; ++j) {
            const int bits = (wm >> (3 * j)) & 7;
            #pragma unroll
            for (int k = 0; k < NC; ++k)
                ind[j][k] = (bits == (4 | k)) ? 1.f : 0.f;
        }

        float vsq[4] = {0.f, 0.f, 0.f, 0.f};
        #pragma unroll
        for (int half = 0; half < 2; ++half) {
            float4 fv[8];
            #pragma unroll
            for (int u = 0; u < 8; ++u) fv[u] = make_float4(0.f, 0.f, 0.f, 0.f);
            if (act) {
                #pragma unroll
                for (int u = 0; u < 8; ++u)
                    fv[u] = fb[(size_t)(c0 + half * 8 + u) * PLANE4 + gg];
            }
            #pragma unroll
            for (int u = 0; u < 8; ++u) {
                const int uc = half * 8 + u;
                #pragma unroll
                for (int j = 0; j < 4; ++j) {
                    const float v = ((const float*)&fv[u])[j];
                    vsq[j] = fmaf(v, v, vsq[j]);
                    #pragma unroll
                    for (int k = 0; k < NC; ++k)
                        acc[uc * 4 + k] = fmaf(ind[j][k], v, acc[uc * 4 + k]);
                }
            }
        }
        #pragma unroll
        for (int j = 0; j < 4; ++j)
            #pragma unroll
            for (int k = 0; k < NC; ++k)
                sq[k] = fmaf(ind[j][k], vsq[j], sq[k]);
    }

    // ---- multi-value butterfly reduce-scatter: lane L ends with total of
    //      value index L (channel c0 + (L>>2), class L&3) over all 64 lanes ----
    #pragma unroll
    for (int s = 5; s >= 0; --s) {
        const int m = 1 << s;
        #pragma unroll
        for (int i = 0; i < (1 << s); ++i) {
            const bool hi = (l & m) != 0;
            const float send = hi ? acc[i] : acc[i + m];
            const float recv = __shfl_xor(send, m);
            acc[i] = (hi ? acc[i + m] : acc[i]) + recv;
        }
    }

    float* dst = part + (size_t)(bi & (NPART - 1)) * PARTSZ;
    const float tot = acc[0];
    const int cc = c0 + (l >> 2), kk = l & 3;
    if (tot != 0.f) atomicAdd(&dst[kk * 64 + cc], tot);

    // per-wave sumsq butterfly + flush
    #pragma unroll
    for (int k = 0; k < NC; ++k) {
        float v = sq[k];
        #pragma unroll
        for (int o = 1; o < 64; o <<= 1) v += __shfl_xor(v, o);
        sq[k] = v;
    }
    if (l < NC) {
        float v = (l == 0) ? sq[0] : (l == 1) ? sq[1] : (l == 2) ? sq[2] : sq[3];
        if (v != 0.f) atomicAdd(&dst[260 + l], v);
    }
    if (t < NC) { float c = lcnt[t]; if (c != 0.f) atomicAdd(&dst[256 + t], c); }
}

__global__ __launch_bounds__(256) void pm_pass2(
    const float* __restrict__ part, const float* __restrict__ proto,
    float* __restrict__ out)
{
    __shared__ float scnt[NC], ssq[NC], smu[NC * CCH], sred[4];
    __shared__ float s_intra;
    const int t = threadIdx.x;
    const int q = t >> 6;

    float s = 0.f;
    #pragma unroll
    for (int p = 0; p < NPART; ++p) s += part[p * PARTSZ + t];
    if (t < 2 * NC) {
        float a = 0.f;
        #pragma unroll
        for (int p = 0; p < NPART; ++p) a += part[p * PARTSZ + 256 + t];
        if (t < NC) scnt[t] = a; else ssq[t - NC] = a;
    }
    __syncthreads();

    const float cq = scnt[q];
    const float mean = s / fmaxf(cq, 1.f);
    const float pold = proto[t];                       // (4,64) row-major == t
    const float mu = (cq > 0.f) ? 0.9f * pold + 0.1f * mean : pold;
    out[3 + t] = mu;
    smu[t] = mu;

    // loss_intra numerator partial: -2*sums*mu + cnt*mu^2  (sumsq added at the end)
    float pi = -2.f * s * mu + cq * mu * mu;
    #pragma unroll
    for (int o = 1; o < 64; o <<= 1) pi += __shfl_xor(pi, o);
    if ((t & 63) == 0) sred[t >> 6] = pi;
    __syncthreads();

    if (t == 0) {
        float num = sred[0] + sred[1] + sred[2] + sred[3]
                  + ssq[0] + ssq[1] + ssq[2] + ssq[3];
        float nv = scnt[0] + scnt[1] + scnt[2] + scnt[3];
        s_intra = num / fmaxf(nv, 1.f);
    }
    __syncthreads();

    if (t < 64) {
        const int pi_[6] = {0, 0, 0, 1, 1, 2};
        const int pj_[6] = {1, 2, 3, 2, 3, 3};
        float acc = 0.f;
        #pragma unroll
        for (int e = 0; e < 6; ++e) {
            float d = smu[pi_[e] * 64 + t] - smu[pj_[e] * 64 + t];
            float d2 = d * d;
            #pragma unroll
            for (int o = 1; o < 64; o <<= 1) d2 += __shfl_xor(d2, o);
            float dist = sqrtf(d2 + 1e-12f);
            float vv = fmaxf(1.f - dist, 0.f);
            acc += vv * vv;
        }
        if (t == 0) {
            float li = acc / 6.f;                      // n_pairs = 6
            out[0] = s_intra + 0.1f * li;              // lambda_intra=1, lambda_inter=0.1
            out[1] = s_intra;
            out[2] = li;
        }
    }
}

extern "C" void kernel_launch(void* const* d_in, const int* in_sizes, int n_in,
                              void* d_out, int out_size, void* d_ws, size_t ws_size,
                              hipStream_t stream) {
    const float* feat         = (const float*)d_in[0];
    const float* pred         = (const float*)d_in[1];
    const int* label          = (const int*)d_in[2];
    const unsigned char* ilab = (const unsigned char*)d_in[3];   // jnp bool = 1 byte
    const float* proto        = (const float*)d_in[4];
    float* out                = (float*)d_out;
    float* part               = (float*)d_ws;

    hipLaunchKernelGGL(pm_zero, dim3(1),    dim3(256), 0, stream, part);
    hipLaunchKernelGGL(pm_main, dim3(NBLK), dim3(256), 0, stream,
                       feat, pred, label, ilab, part);
    hipLaunchKernelGGL(pm_pass2, dim3(1),   dim3(256), 0, stream, part, proto, out);
}

// Round 11
// 109.537 us; speedup vs baseline: 6.8944x; 6.8944x over previous
//
#include <hip/hip_runtime.h>

#define HWD 884736   // 96*96*96
#define KCLS 5
#define CCH 64
#define NC 4

constexpr int PLANE4 = HWD / 4;          // float4 groups per channel plane (221184)
constexpr int GRP_B  = HWD / 4;          // voxel-groups per batch item
constexpr int NBLK   = 2 * GRP_B / 256;  // 1728 blocks of 256 groups
constexpr int NPART  = 16;
constexpr int PARTSZ = 272;              // 256 sums + 4 cnt @256 + 4 sq @260

__global__ __launch_bounds__(256) void pm_zero(float* __restrict__ part) {
    const int n = NPART * PARTSZ;
    for (int i = threadIdx.x; i < n; i += 256) part[i] = 0.f;
}

// acc is float4[16]; flat index f in [0,64): channel-in-wave f>>2, class f&3.
// All indices compile-time after unrolling (rule #20: no runtime indexing).
#define ACCF(i) (((float*)&acc[(i) >> 2])[(i) & 3])

// One butterfly reduce-scatter stage with LITERAL count/mask.
#define RSTAGE(M, CNT)                                                  \
    {                                                                   \
        _Pragma("unroll")                                               \
        for (int i = 0; i < CNT; ++i) {                                 \
            const float send = hi##M ? ACCF(i) : ACCF(i + M);           \
            const float recv = __shfl_xor(send, M);                     \
            ACCF(i) = (hi##M ? ACCF(i + M) : ACCF(i)) + recv;           \
        }                                                               \
    }

// Fused: mask (pred/label -> 3b/voxel in LDS) + dense coalesced feat sweep,
// register-resident accumulation + in-register butterfly reduce-scatter.
__global__ __launch_bounds__(256, 3) void pm_main(
    const float* __restrict__ feat, const float* __restrict__ pred,
    const int* __restrict__ label, const unsigned char* __restrict__ is_lab,
    float* __restrict__ part)
{
    __shared__ unsigned int smask[256];
    __shared__ float lcnt[NC];

    const int t = threadIdx.x, w = t >> 6, l = t & 63;
    const int bi = blockIdx.x;
    const int b = (bi >= NBLK / 2);                  // block never straddles batch
    const int g0 = bi * 256 - b * GRP_B;             // group base within batch plane

    if (t < NC) lcnt[t] = 0.f;
    __syncthreads();

    // ---- phase A: mask from pred/label (coalesced), one group per thread ----
    {
        const int gg = g0 + t;
        const float4* pb = (const float4*)(pred + (size_t)b * KCLS * HWD) + gg;
        float4 pk[KCLS];
        #pragma unroll
        for (int k = 0; k < KCLS; ++k) pk[k] = pb[(size_t)k * PLANE4];
        const int4 lb = ((const int4*)(label + (size_t)b * HWD))[gg];
        const bool lab = is_lab[b] != 0;

        unsigned int wd = 0;
        #pragma unroll
        for (int j = 0; j < 4; ++j) {
            float best = -1.f; int c = 0;
            #pragma unroll
            for (int k = 0; k < KCLS; ++k) {
                float v = ((const float*)&pk[k])[j];
                if (v > best) { best = v; c = k; }   // first-max == jnp.argmax
            }
            const int lj = ((const int*)&lb)[j];
            const bool m = (best > 0.8f) & (c > 0) & ((c == lj) | (!lab));
            if (m) {
                wd |= (4u | (unsigned)(c - 1)) << (3 * j);
                atomicAdd(&lcnt[c - 1], 1.f);
            }
        }
        smask[t] = wd;
    }
    __syncthreads();

    // ---- phase B: dense sweep; wave w owns channels [16w, 16w+16) ----
    const float4* fb = (const float4*)feat + (size_t)b * CCH * PLANE4;
    const int c0 = w * 16;

    float4 acc[16];
    #pragma unroll
    for (int u = 0; u < 16; ++u) acc[u] = make_float4(0.f, 0.f, 0.f, 0.f);
    float sq[NC] = {0.f, 0.f, 0.f, 0.f};

    for (int i = 0; i < 4; ++i) {
        const int gl = i * 64 + l;                   // group within block
        const int gg = g0 + gl;
        const unsigned int wm = smask[gl];

        float ind[4][NC];
        #pragma unroll
        for (int j = 0; j < 4; ++j) {
            const int bits = (wm >> (3 * j)) & 7;
            #pragma unroll
            for (int k = 0; k < NC; ++k)
                ind[j][k] = (bits == (4 | k)) ? 1.f : 0.f;
        }

        float vsq[4] = {0.f, 0.f, 0.f, 0.f};
        #pragma unroll
        for (int half = 0; half < 2; ++half) {
            float4 fv[8];
            #pragma unroll
            for (int u = 0; u < 8; ++u)
                fv[u] = fb[(size_t)(c0 + half * 8 + u) * PLANE4 + gg];  // 8 coalesced 1KB loads
            #pragma unroll
            for (int u = 0; u < 8; ++u) {
                const int uc = half * 8 + u;
                #pragma unroll
                for (int j = 0; j < 4; ++j) {
                    const float v = ((const float*)&fv[u])[j];
                    vsq[j] = fmaf(v, v, vsq[j]);
                    #pragma unroll
                    for (int k = 0; k < NC; ++k)
                        ((float*)&acc[uc])[k] = fmaf(ind[j][k], v, ((float*)&acc[uc])[k]);
                }
            }
        }
        #pragma unroll
        for (int j = 0; j < 4; ++j)
            #pragma unroll
            for (int k = 0; k < NC; ++k)
                sq[k] = fmaf(ind[j][k], vsq[j], sq[k]);
    }

    // ---- 6-stage butterfly reduce-scatter: lane L ends with the block-wave
    //      total for flat index L (channel c0 + (L>>2), class L&3) ----
    {
        const bool hi32 = (l & 32) != 0;  RSTAGE(32, 32)
        const bool hi16 = (l & 16) != 0;  RSTAGE(16, 16)
        const bool hi8  = (l & 8)  != 0;  RSTAGE(8, 8)
        const bool hi4  = (l & 4)  != 0;  RSTAGE(4, 4)
        const bool hi2  = (l & 2)  != 0;  RSTAGE(2, 2)
        const bool hi1  = (l & 1)  != 0;  RSTAGE(1, 1)
    }

    float* dst = part + (size_t)(bi & (NPART - 1)) * PARTSZ;
    {
        const float tot = ACCF(0);
        const int cc = c0 + (l >> 2), kk = l & 3;
        if (tot != 0.f) atomicAdd(&dst[kk * 64 + cc], tot);
    }

    // per-wave sumsq butterfly + flush
    #pragma unroll
    for (int k = 0; k < NC; ++k) {
        float v = sq[k];
        #pragma unroll
        for (int o = 1; o < 64; o <<= 1) v += __shfl_xor(v, o);
        sq[k] = v;
    }
    if (l < NC) {
        float v = (l == 0) ? sq[0] : (l == 1) ? sq[1] : (l == 2) ? sq[2] : sq[3];
        if (v != 0.f) atomicAdd(&dst[260 + l], v);
    }
    if (t < NC) { float c = lcnt[t]; if (c != 0.f) atomicAdd(&dst[256 + t], c); }
}

__global__ __launch_bounds__(256) void pm_pass2(
    const float* __restrict__ part, const float* __restrict__ proto,
    float* __restrict__ out)
{
    __shared__ float scnt[NC], ssq[NC], smu[NC * CCH], sred[4];
    __shared__ float s_intra;
    const int t = threadIdx.x;
    const int q = t >> 6;

    float s = 0.f;
    #pragma unroll
    for (int p = 0; p < NPART; ++p) s += part[p * PARTSZ + t];
    if (t < 2 * NC) {
        float a = 0.f;
        #pragma unroll
        for (int p = 0; p < NPART; ++p) a += part[p * PARTSZ + 256 + t];
        if (t < NC) scnt[t] = a; else ssq[t - NC] = a;
    }
    __syncthreads();

    const float cq = scnt[q];
    const float mean = s / fmaxf(cq, 1.f);
    const float pold = proto[t];                       // (4,64) row-major == t
    const float mu = (cq > 0.f) ? 0.9f * pold + 0.1f * mean : pold;
    out[3 + t] = mu;
    smu[t] = mu;

    // loss_intra numerator partial: -2*sums*mu + cnt*mu^2  (sumsq added at the end)
    float pi = -2.f * s * mu + cq * mu * mu;
    #pragma unroll
    for (int o = 1; o < 64; o <<= 1) pi += __shfl_xor(pi, o);
    if ((t & 63) == 0) sred[t >> 6] = pi;
    __syncthreads();

    if (t == 0) {
        float num = sred[0] + sred[1] + sred[2] + sred[3]
                  + ssq[0] + ssq[1] + ssq[2] + ssq[3];
        float nv = scnt[0] + scnt[1] + scnt[2] + scnt[3];
        s_intra = num / fmaxf(nv, 1.f);
    }
    __syncthreads();

    if (t < 64) {
        const int pi_[6] = {0, 0, 0, 1, 1, 2};
        const int pj_[6] = {1, 2, 3, 2, 3, 3};
        float acc = 0.f;
        #pragma unroll
        for (int e = 0; e < 6; ++e) {
            float d = smu[pi_[e] * 64 + t] - smu[pj_[e] * 64 + t];
            float d2 = d * d;
            #pragma unroll
            for (int o = 1; o < 64; o <<= 1) d2 += __shfl_xor(d2, o);
            float dist = sqrtf(d2 + 1e-12f);
            float vv = fmaxf(1.f - dist, 0.f);
            acc += vv * vv;
        }
        if (t == 0) {
            float li = acc / 6.f;                      // n_pairs = 6
            out[0] = s_intra + 0.1f * li;              // lambda_intra=1, lambda_inter=0.1
            out[1] = s_intra;
            out[2] = li;
        }
    }
}

extern "C" void kernel_launch(void* const* d_in, const int* in_sizes, int n_in,
                              void* d_out, int out_size, void* d_ws, size_t ws_size,
                              hipStream_t stream) {
    const float* feat         = (const float*)d_in[0];
    const float* pred         = (const float*)d_in[1];
    const int* label          = (const int*)d_in[2];
    const unsigned char* ilab = (const unsigned char*)d_in[3];   // jnp bool = 1 byte
    const float* proto        = (const float*)d_in[4];
    float* out                = (float*)d_out;
    float* part               = (float*)d_ws;

    hipLaunchKernelGGL(pm_zero, dim3(1),    dim3(256), 0, stream, part);
    hipLaunchKernelGGL(pm_main, dim3(NBLK), dim3(256), 0, stream,
                       feat, pred, label, ilab, part);
    hipLaunchKernelGGL(pm_pass2, dim3(1),   dim3(256), 0, stream, part, proto, out);
}